// Round 7
// baseline (695.002 us; speedup 1.0000x reference)
//
#include <hip/hip_runtime.h>
#include <math.h>

#define NHEAD 16
#define DK 64
#define DMODEL 1024
#define BB 2
#define LQ 2048
#define LK 2048
#define MROWS (BB * LQ)  // 4096
#define PLANE ((size_t)MROWS * DMODEL)   // 4M elems
#define WPLANE ((size_t)DMODEL * DMODEL) // 1M elems

typedef __attribute__((ext_vector_type(8))) short short8v;   // 8 bf16 (4 VGPR)
typedef __attribute__((ext_vector_type(4))) float f32x4;
typedef __attribute__((ext_vector_type(16))) float f32x16;
typedef __attribute__((ext_vector_type(4))) uint uint4v;

__device__ __forceinline__ ushort f2bf(float x) {  // RNE fp32->bf16
  uint u = __builtin_bit_cast(uint, x);
  u += 0x7FFFu + ((u >> 16) & 1u);
  return (ushort)(u >> 16);
}
__device__ __forceinline__ float bf2f(ushort h) {
  return __builtin_bit_cast(float, ((uint)h) << 16);
}

// ---------------------------------------------------------------------------
// pack_mask: int32 mask [B,LQ,LK] -> bit-packed words (1 MB, L2-resident).
// wave reads 64 consecutive ints coalesced, __ballot -> 2 words.
// ---------------------------------------------------------------------------
__global__ __launch_bounds__(256) void pack_mask(const int* __restrict__ mask,
                                                 uint* __restrict__ bits) {
  const int nPairs = BB * LQ * (LK / 32) / 2;  // 131072
  const int wid = threadIdx.x >> 6, ln = threadIdx.x & 63;
  const int nw = gridDim.x * 4;
  for (int p = blockIdx.x * 4 + wid; p < nPairs; p += nw) {
    const int m = mask[(size_t)p * 64 + ln];
    unsigned long long bal = __ballot(m != 0);
    if (ln == 0) bits[p * 2] = (uint)bal;
    if (ln == 32) bits[p * 2 + 1] = (uint)(bal >> 32);
  }
}

// ---------------------------------------------------------------------------
// conv_x3: q,k,v fp32 -> hi/lo bf16 planes in one launch (z picks tensor).
// ---------------------------------------------------------------------------
__global__ __launch_bounds__(256) void conv_x3(
    const float* __restrict__ q, const float* __restrict__ k,
    const float* __restrict__ v, ushort* __restrict__ hiB,
    ushort* __restrict__ loB, int n4) {
  const int z = blockIdx.z;
  const float* x = z == 0 ? q : z == 1 ? k : v;
  ushort* hi = hiB + (size_t)z * PLANE;
  ushort* lo = loB + (size_t)z * PLANE;
  for (int i = blockIdx.x * blockDim.x + threadIdx.x; i < n4;
       i += gridDim.x * blockDim.x) {
    float4 vv = ((const float4*)x)[i];
    ushort4 h, l;
    h.x = f2bf(vv.x); l.x = f2bf(vv.x - bf2f(h.x));
    h.y = f2bf(vv.y); l.y = f2bf(vv.y - bf2f(h.y));
    h.z = f2bf(vv.z); l.z = f2bf(vv.z - bf2f(h.z));
    h.w = f2bf(vv.w); l.w = f2bf(vv.w - bf2f(h.w));
    ((ushort4*)hi)[i] = h;
    ((ushort4*)lo)[i] = l;
  }
}

// ---------------------------------------------------------------------------
// conv_wT: W[1024,1024] fp32 [k][n] -> transposed hi/lo planes [n][k].
// ---------------------------------------------------------------------------
__global__ __launch_bounds__(256) void conv_wT(
    const float* __restrict__ w0, const float* __restrict__ w1,
    const float* __restrict__ w2, const float* __restrict__ w3,
    ushort* __restrict__ hiB, ushort* __restrict__ loB) {
  const float* W = blockIdx.z == 0 ? w0
                   : blockIdx.z == 1 ? w1
                   : blockIdx.z == 2 ? w2 : w3;
  ushort* hi = hiB + (size_t)blockIdx.z * WPLANE;
  ushort* lo = loB + (size_t)blockIdx.z * WPLANE;
  __shared__ ushort Th[64][66], Tl[64][66];
  const int t = threadIdx.x;
  const int n0 = blockIdx.x * 64, k0 = blockIdx.y * 64;
  const int r = t >> 4, c4 = (t & 15) << 2;
#pragma unroll
  for (int p = 0; p < 4; ++p) {
    const int kr = r + p * 16;
    float4 v = *(const float4*)&W[(size_t)(k0 + kr) * DMODEL + n0 + c4];
    ushort h;
    h = f2bf(v.x); Th[c4 + 0][kr] = h; Tl[c4 + 0][kr] = f2bf(v.x - bf2f(h));
    h = f2bf(v.y); Th[c4 + 1][kr] = h; Tl[c4 + 1][kr] = f2bf(v.y - bf2f(h));
    h = f2bf(v.z); Th[c4 + 2][kr] = h; Tl[c4 + 2][kr] = f2bf(v.z - bf2f(h));
    h = f2bf(v.w); Th[c4 + 3][kr] = h; Tl[c4 + 3][kr] = f2bf(v.w - bf2f(h));
  }
  __syncthreads();
  const int n = t >> 2, g = t & 3;
  uint uh[8], ul[8];
#pragma unroll
  for (int j = 0; j < 8; ++j) {
    uh[j] = *(const uint*)&Th[n][g * 16 + 2 * j];
    ul[j] = *(const uint*)&Tl[n][g * 16 + 2 * j];
  }
  const size_t ob = (size_t)(n0 + n) * DMODEL + k0 + g * 16;
  *(uint4*)&hi[ob] = make_uint4(uh[0], uh[1], uh[2], uh[3]);
  *(uint4*)&hi[ob + 8] = make_uint4(uh[4], uh[5], uh[6], uh[7]);
  *(uint4*)&lo[ob] = make_uint4(ul[0], ul[1], ul[2], ul[3]);
  *(uint4*)&lo[ob + 8] = make_uint4(ul[4], ul[5], ul[6], ul[7]);
}

// ---------------------------------------------------------------------------
// Split-bf16 MFMA GEMM from pre-split planes (unchanged from round 6).
// MODE 3: batched projections (z in {0,1,2}; z==2 -> V^T planes).
// MODE 1: fp32 out [m,1024] + residual (fc).
// ---------------------------------------------------------------------------
template <int MODE>
__global__ __launch_bounds__(256, 2) void gemm_mfma(
    const ushort* __restrict__ Ah, const ushort* __restrict__ Al,
    const ushort* __restrict__ Bh, const ushort* __restrict__ Bl,
    ushort* __restrict__ Oh, ushort* __restrict__ Ol,
    float* __restrict__ outF, const float* __restrict__ res) {
  __shared__ __align__(16) ushort As_hi[128 * 32], As_lo[128 * 32];
  __shared__ __align__(16) ushort Bs_hi[128 * 32], Bs_lo[128 * 32];

  const int t = threadIdx.x;
  const int ln = t & 63, wv = t >> 6;
  const int wm = wv >> 1, wn = wv & 1;
  const int n0 = blockIdx.x * 128, m0 = blockIdx.y * 128;
  const int zz = blockIdx.z;

  if (MODE == 3) {
    Ah += (size_t)zz * PLANE;  Al += (size_t)zz * PLANE;
    Bh += (size_t)zz * WPLANE; Bl += (size_t)zz * WPLANE;
    Oh += (size_t)zz * PLANE;  Ol += (size_t)zz * PLANE;
  }

  const int am = t & 127, akg = t >> 7;

  const ushort* Aph = Ah + (size_t)(m0 + am) * 1024 + akg * 16;
  const ushort* Apl = Al + (size_t)(m0 + am) * 1024 + akg * 16;
  const ushort* Bph = Bh + (size_t)(n0 + am) * 1024 + akg * 16;
  const ushort* Bpl = Bl + (size_t)(n0 + am) * 1024 + akg * 16;

  short8v ah0 = *(const short8v*)(Aph), ah1 = *(const short8v*)(Aph + 8);
  short8v al0 = *(const short8v*)(Apl), al1 = *(const short8v*)(Apl + 8);
  short8v bh0 = *(const short8v*)(Bph), bh1 = *(const short8v*)(Bph + 8);
  short8v bl0 = *(const short8v*)(Bpl), bl1 = *(const short8v*)(Bpl + 8);

  f32x4 acc[4][4];
#pragma unroll
  for (int i = 0; i < 4; ++i)
#pragma unroll
    for (int j = 0; j < 4; ++j)
#pragma unroll
      for (int r = 0; r < 4; ++r) acc[i][j][r] = 0.f;

  const int swa = (am >> 1) & 3;
  const int s0 = (akg * 2) ^ swa, s1 = (akg * 2 + 1) ^ swa;

  for (int k0 = 0; k0 < 1024; k0 += 32) {
    __syncthreads();
    *(short8v*)&As_hi[am * 32 + s0 * 8] = ah0;
    *(short8v*)&As_hi[am * 32 + s1 * 8] = ah1;
    *(short8v*)&As_lo[am * 32 + s0 * 8] = al0;
    *(short8v*)&As_lo[am * 32 + s1 * 8] = al1;
    *(short8v*)&Bs_hi[am * 32 + s0 * 8] = bh0;
    *(short8v*)&Bs_hi[am * 32 + s1 * 8] = bh1;
    *(short8v*)&Bs_lo[am * 32 + s0 * 8] = bl0;
    *(short8v*)&Bs_lo[am * 32 + s1 * 8] = bl1;
    __syncthreads();

    if (k0 + 32 < 1024) {
      ah0 = *(const short8v*)(Aph + k0 + 32);
      ah1 = *(const short8v*)(Aph + k0 + 40);
      al0 = *(const short8v*)(Apl + k0 + 32);
      al1 = *(const short8v*)(Apl + k0 + 40);
      bh0 = *(const short8v*)(Bph + k0 + 32);
      bh1 = *(const short8v*)(Bph + k0 + 40);
      bl0 = *(const short8v*)(Bpl + k0 + 32);
      bl1 = *(const short8v*)(Bpl + k0 + 40);
    }

    short8v fah[4], fal[4], fbh[4], fbl[4];
#pragma unroll
    for (int mf = 0; mf < 4; ++mf) {
      const int mr = wm * 64 + mf * 16 + (ln & 15);
      const int sl = (ln >> 4) ^ ((mr >> 1) & 3);
      fah[mf] = *(const short8v*)&As_hi[mr * 32 + sl * 8];
      fal[mf] = *(const short8v*)&As_lo[mr * 32 + sl * 8];
    }
#pragma unroll
    for (int nf = 0; nf < 4; ++nf) {
      const int nr = wn * 64 + nf * 16 + (ln & 15);
      const int sl = (ln >> 4) ^ ((nr >> 1) & 3);
      fbh[nf] = *(const short8v*)&Bs_hi[nr * 32 + sl * 8];
      fbl[nf] = *(const short8v*)&Bs_lo[nr * 32 + sl * 8];
    }
#pragma unroll
    for (int mi = 0; mi < 4; ++mi)
#pragma unroll
      for (int ni = 0; ni < 4; ++ni) {
        acc[mi][ni] = __builtin_amdgcn_mfma_f32_16x16x32_bf16(
            fah[mi], fbh[ni], acc[mi][ni], 0, 0, 0);
        acc[mi][ni] = __builtin_amdgcn_mfma_f32_16x16x32_bf16(
            fal[mi], fbh[ni], acc[mi][ni], 0, 0, 0);
        acc[mi][ni] = __builtin_amdgcn_mfma_f32_16x16x32_bf16(
            fah[mi], fbl[ni], acc[mi][ni], 0, 0, 0);
      }
  }

#pragma unroll
  for (int mi = 0; mi < 4; ++mi)
#pragma unroll
    for (int ni = 0; ni < 4; ++ni) {
      const int ng = n0 + wn * 64 + ni * 16 + (ln & 15);
#pragma unroll
      for (int r = 0; r < 4; ++r) {
        const int mg = m0 + wm * 64 + mi * 16 + (ln >> 4) * 4 + r;
        const float val = acc[mi][ni][r];
        if (MODE == 1) {
          outF[(size_t)mg * 1024 + ng] = val + res[(size_t)mg * 1024 + ng];
        } else {
          const int h = ng >> 6, d = ng & 63;
          const int bb = mg >> 11, l = mg & (LQ - 1);
          size_t idx;
          if (zz == 2) idx = ((size_t)(bb * NHEAD + h) * 64 + d) * LK + l;
          else         idx = ((size_t)(bb * NHEAD + h) * LQ + l) * 64 + d;
          const ushort hb = f2bf(val);
          Oh[idx] = hb;
          Ol[idx] = f2bf(val - bf2f(hb));
        }
      }
    }
}

// ---------------------------------------------------------------------------
// MFMA flash attention, split-KV x2 (blockIdx.z = b*2 + khalf), dbuf LDS
// (1 barrier/iter), bit-packed mask (1 dword/lane/iter), P in registers.
// Emits unnormalized O partials (fp32) + (m,l) per q-row; merge_attn combines.
// ---------------------------------------------------------------------------
__global__ __launch_bounds__(256, 4) void attn_mfma(
    const ushort* __restrict__ Qhh, const ushort* __restrict__ Qhl,
    const ushort* __restrict__ Khh, const ushort* __restrict__ Khl,
    const ushort* __restrict__ VTh, const ushort* __restrict__ VTl,
    const uint* __restrict__ mbits, const float* __restrict__ mean,
    const float* __restrict__ stdv, float* __restrict__ Opart,
    float* __restrict__ MLpart) {
  __shared__ __align__(16) ushort Ks_hi[2][32 * 64], Ks_lo[2][32 * 64];
  __shared__ __align__(16) ushort VT_hi[2][64 * 40], VT_lo[2][64 * 40];
  __shared__ float sc_lds[4][32];

  const int t = threadIdx.x;
  const int w = t >> 6, ln = t & 63;
  const int lq = ln & 31;
  const int hi5 = ln >> 5;

  const int q0 = blockIdx.x * 128 + w * 32;
  const int h = blockIdx.y;
  const int bz = blockIdx.z, b = bz >> 1, kh = bz & 1;
  const int kbase = kh * (LK / 2);
  const int NIT = (LK / 2) / 32;  // 32 iterations

  Opart += (size_t)kh * PLANE;
  MLpart += (size_t)kh * ((size_t)BB * NHEAD * LQ * 2);

  const size_t hb_ = (size_t)(b * NHEAD + h);
  const ushort* Qh_ = Qhh + hb_ * LQ * 64;
  const ushort* Ql_ = Qhl + hb_ * LQ * 64;
  const ushort* Kh_ = Khh + hb_ * LK * 64 + (size_t)kbase * 64;
  const ushort* Kl_ = Khl + hb_ * LK * 64 + (size_t)kbase * 64;
  const ushort* Vh_ = VTh + hb_ * 64 * LK + kbase;  // [d][l], col offset
  const ushort* Vl_ = VTl + hb_ * 64 * LK + kbase;

  // ---- Q fragments (B-operand; lane col q = ln&31) ----
  short8v qf_h[4], qf_l[4];
#pragma unroll
  for (int ds = 0; ds < 4; ++ds) {
    const size_t off = (size_t)(q0 + lq) * 64 + ds * 16 + hi5 * 8;
    qf_h[ds] = *(const short8v*)&Qh_[off];
    qf_l[ds] = *(const short8v*)&Ql_[off];
  }

  // staging assignments
  const int skr = t >> 3, sds = t & 7;  // K: row 0..31, 8-d slot
  const int vd = t >> 2, vg = t & 3;    // V^T: d-row 0..63, 8-k group
  const int kslot = sds ^ (skr & 7);

  // tile 0 -> regs -> buf0
  short8v kp_h = *(const short8v*)&Kh_[(size_t)skr * 64 + sds * 8];
  short8v kp_l = *(const short8v*)&Kl_[(size_t)skr * 64 + sds * 8];
  short8v vp_h = *(const short8v*)&Vh_[(size_t)vd * LK + vg * 8];
  short8v vp_l = *(const short8v*)&Vl_[(size_t)vd * LK + vg * 8];
  *(short8v*)&Ks_hi[0][skr * 64 + kslot * 8] = kp_h;
  *(short8v*)&Ks_lo[0][skr * 64 + kslot * 8] = kp_l;
  *(short8v*)&VT_hi[0][vd * 40 + vg * 8] = vp_h;
  *(short8v*)&VT_lo[0][vd * 40 + vg * 8] = vp_l;
  __syncthreads();

  f32x16 Oa[2];
#pragma unroll
  for (int dt = 0; dt < 2; ++dt)
#pragma unroll
    for (int r = 0; r < 16; ++r) Oa[dt][r] = 0.f;
  float mrun = -INFINITY, lrun = 0.f;

  const size_t mrow = ((size_t)(b * LQ + q0 + lq)) * 64 + kh * 32;

  for (int it = 0; it < NIT; ++it) {
    const int k0 = it * 32;
    const int cur = it & 1;

    // current-iter small loads first (oldest in vm queue)
    const uint mw = mbits[mrow + it];
    float4 mn[4], sd[4];
#pragma unroll
    for (int g = 0; g < 4; ++g) {
      const int kb = kbase + k0 + 8 * g + 4 * hi5;
      mn[g] = *(const float4*)&mean[(size_t)b * LK + kb];
      sd[g] = *(const float4*)&stdv[(size_t)b * LK + kb];
    }

    if (it + 1 < NIT) {  // prefetch next K/V tile into regs
      const int nk = k0 + 32;
      kp_h = *(const short8v*)&Kh_[(size_t)(nk + skr) * 64 + sds * 8];
      kp_l = *(const short8v*)&Kl_[(size_t)(nk + skr) * 64 + sds * 8];
      vp_h = *(const short8v*)&Vh_[(size_t)vd * LK + nk + vg * 8];
      vp_l = *(const short8v*)&Vl_[(size_t)vd * LK + nk + vg * 8];
    }

    // ---- S^T = K·Q^T over d (4 segs x 3 split-terms) ----
    f32x16 S;
#pragma unroll
    for (int r = 0; r < 16; ++r) S[r] = 0.f;
#pragma unroll
    for (int ds = 0; ds < 4; ++ds) {
      const int dsl = (ds * 2 + hi5) ^ (lq & 7);
      short8v kf_h = *(const short8v*)&Ks_hi[cur][lq * 64 + dsl * 8];
      short8v kf_l = *(const short8v*)&Ks_lo[cur][lq * 64 + dsl * 8];
      S = __builtin_amdgcn_mfma_f32_32x32x16_bf16(kf_h, qf_h[ds], S, 0, 0, 0);
      S = __builtin_amdgcn_mfma_f32_32x32x16_bf16(kf_l, qf_h[ds], S, 0, 0, 0);
      S = __builtin_amdgcn_mfma_f32_32x32x16_bf16(kf_h, qf_l[ds], S, 0, 0, 0);
    }

    // ---- affine + bitmask + online softmax (lane owns q = lq) ----
    float p[16];
    float tmax = -INFINITY;
#pragma unroll
    for (int r = 0; r < 16; ++r) {
      const int g = r >> 2, j = r & 3;
      const int kit = (r & 3) + 8 * (r >> 2) + 4 * hi5;
      float v = fmaf(S[r], ((const float*)&mn[g])[j] * 0.125f,
                     ((const float*)&sd[g])[j] * 0.125f);
      v = ((mw >> kit) & 1u) ? v : -1e9f;
      p[r] = v;
      tmax = fmaxf(tmax, v);
    }
    tmax = fmaxf(tmax, __shfl_xor(tmax, 32, 64));
    const bool need = __any(tmax > mrun);
    const float mnew = need ? fmaxf(mrun, tmax) : mrun;
    float psum = 0.f;
#pragma unroll
    for (int r = 0; r < 16; ++r) {
      p[r] = __expf(p[r] - mnew);
      psum += p[r];
    }
    psum += __shfl_xor(psum, 32, 64);
    if (need) {
      const float scl = __expf(mrun - mnew);
      lrun = lrun * scl + psum;
      mrun = mnew;
      sc_lds[w][lq] = scl;
      float4 s4[4];
#pragma unroll
      for (int g = 0; g < 4; ++g)
        s4[g] = *(const float4*)&sc_lds[w][8 * g + 4 * hi5];
#pragma unroll
      for (int dt = 0; dt < 2; ++dt)
#pragma unroll
        for (int r = 0; r < 16; ++r)
          Oa[dt][r] *= ((const float*)&s4[r >> 2])[r & 3];
    } else {
      lrun += psum;  // scl == 1 exactly
    }

    // ---- P -> bf16 hi/lo PV A-fragments, in registers ----
    uint ch[8], cl[8];
#pragma unroll
    for (int j = 0; j < 8; ++j) {
      const float a = p[2 * j], c = p[2 * j + 1];
      const ushort h0 = __builtin_bit_cast(ushort, (__bf16)a);
      const ushort h1 = __builtin_bit_cast(ushort, (__bf16)c);
      ch[j] = (uint)h0 | ((uint)h1 << 16);
      const float l0 = a - bf2f(h0);
      const float l1 = c - bf2f(h1);
      const ushort g0 = __builtin_bit_cast(ushort, (__bf16)l0);
      const ushort g1 = __builtin_bit_cast(ushort, (__bf16)l1);
      cl[j] = (uint)g0 | ((uint)g1 << 16);
    }
    asm("v_permlane32_swap_b32 %0, %1" : "+v"(ch[0]), "+v"(ch[2]));
    asm("v_permlane32_swap_b32 %0, %1" : "+v"(ch[1]), "+v"(ch[3]));
    asm("v_permlane32_swap_b32 %0, %1" : "+v"(ch[4]), "+v"(ch[6]));
    asm("v_permlane32_swap_b32 %0, %1" : "+v"(ch[5]), "+v"(ch[7]));
    asm("v_permlane32_swap_b32 %0, %1" : "+v"(cl[0]), "+v"(cl[2]));
    asm("v_permlane32_swap_b32 %0, %1" : "+v"(cl[1]), "+v"(cl[3]));
    asm("v_permlane32_swap_b32 %0, %1" : "+v"(cl[4]), "+v"(cl[6]));
    asm("v_permlane32_swap_b32 %0, %1" : "+v"(cl[5]), "+v"(cl[7]));
    short8v paH[2], paL[2];
    {
      uint4v u;
      u = (uint4v){ch[0], ch[1], ch[2], ch[3]};
      paH[0] = __builtin_bit_cast(short8v, u);
      u = (uint4v){ch[4], ch[5], ch[6], ch[7]};
      paH[1] = __builtin_bit_cast(short8v, u);
      u = (uint4v){cl[0], cl[1], cl[2], cl[3]};
      paL[0] = __builtin_bit_cast(short8v, u);
      u = (uint4v){cl[4], cl[5], cl[6], cl[7]};
      paL[1] = __builtin_bit_cast(short8v, u);
    }

    // ---- PV: O[q][d] += P·V ----
#pragma unroll
    for (int dt = 0; dt < 2; ++dt)
#pragma unroll
      for (int ki = 0; ki < 2; ++ki) {
        short8v vbh =
            *(const short8v*)&VT_hi[cur][(dt * 32 + lq) * 40 + ki * 16 + hi5 * 8];
        short8v vbl =
            *(const short8v*)&VT_lo[cur][(dt * 32 + lq) * 40 + ki * 16 + hi5 * 8];
        Oa[dt] = __builtin_amdgcn_mfma_f32_32x32x16_bf16(paH[ki], vbh, Oa[dt], 0, 0, 0);
        Oa[dt] = __builtin_amdgcn_mfma_f32_32x32x16_bf16(paL[ki], vbh, Oa[dt], 0, 0, 0);
        Oa[dt] = __builtin_amdgcn_mfma_f32_32x32x16_bf16(paH[ki], vbl, Oa[dt], 0, 0, 0);
      }

    // ---- stage next tile into other buffer; single barrier per iter ----
    if (it + 1 < NIT) {
      const int nxt = cur ^ 1;
      *(short8v*)&Ks_hi[nxt][skr * 64 + kslot * 8] = kp_h;
      *(short8v*)&Ks_lo[nxt][skr * 64 + kslot * 8] = kp_l;
      *(short8v*)&VT_hi[nxt][vd * 40 + vg * 8] = vp_h;
      *(short8v*)&VT_lo[nxt][vd * 40 + vg * 8] = vp_l;
    }
    __syncthreads();
  }

  // ---- epilogue: unnormalized O + (m,l) partials ----
  if (hi5 == 0) {
    const size_t mli = (hb_ * LQ + q0 + lq) * 2;
    MLpart[mli] = mrun;
    MLpart[mli + 1] = lrun;
  }
#pragma unroll
  for (int dt = 0; dt < 2; ++dt)
#pragma unroll
    for (int r = 0; r < 16; ++r) {
      const int ql = (r & 3) + 8 * (r >> 2) + 4 * hi5;
      Opart[(size_t)(b * LQ + q0 + ql) * DMODEL + h * 64 + dt * 32 + lq] =
          Oa[dt][r];
    }
}

// ---------------------------------------------------------------------------
// merge_attn: combine the two KV-half partials -> ao hi/lo bf16 planes.
// out = (O0*e^{m0-M} + O1*e^{m1-M}) / (l0*e^{m0-M} + l1*e^{m1-M})
// ---------------------------------------------------------------------------
__global__ __launch_bounds__(256) void merge_attn(
    const float* __restrict__ O0, const float* __restrict__ O1,
    const float* __restrict__ ML0, const float* __restrict__ ML1,
    ushort* __restrict__ aoH, ushort* __restrict__ aoL) {
  const int row = blockIdx.x, t = threadIdx.x;
  const int d4 = t << 2, h = d4 >> 6;
  const int b = row >> 11, q = row & (LQ - 1);
  const size_t mli = ((size_t)(b * NHEAD + h) * LQ + q) * 2;
  const float m0 = ML0[mli], l0 = ML0[mli + 1];
  const float m1 = ML1[mli], l1 = ML1[mli + 1];
  const float M = fmaxf(m0, m1);
  const float a0 = __expf(m0 - M), a1 = __expf(m1 - M);
  const float inv = 1.0f / (l0 * a0 + l1 * a1);
  const size_t base = (size_t)row * DMODEL + d4;
  float4 o0 = *(const float4*)&O0[base];
  float4 o1 = *(const float4*)&O1[base];
  float vx[4] = {(o0.x * a0 + o1.x * a1) * inv, (o0.y * a0 + o1.y * a1) * inv,
                 (o0.z * a0 + o1.z * a1) * inv, (o0.w * a0 + o1.w * a1) * inv};
  ushort4 hh, ll;
  hh.x = f2bf(vx[0]); ll.x = f2bf(vx[0] - bf2f(hh.x));
  hh.y = f2bf(vx[1]); ll.y = f2bf(vx[1] - bf2f(hh.y));
  hh.z = f2bf(vx[2]); ll.z = f2bf(vx[2] - bf2f(hh.z));
  hh.w = f2bf(vx[3]); ll.w = f2bf(vx[3] - bf2f(hh.w));
  *(ushort4*)&aoH[base] = hh;
  *(ushort4*)&aoL[base] = ll;
}

// ---------------------------------------------------------------------------
// In-place row LayerNorm over 1024 elements. One block per row, 256 threads.
// ---------------------------------------------------------------------------
__global__ __launch_bounds__(256) void ln_kernel(float* __restrict__ io,
                                                 const float* __restrict__ gamma,
                                                 const float* __restrict__ beta) {
  const int row = blockIdx.x;
  const int t = threadIdx.x;
  float* base = io + (size_t)row * DMODEL;
  float4 x = *(const float4*)&base[t << 2];
  float s = x.x + x.y + x.z + x.w;
#pragma unroll
  for (int xm = 1; xm < 64; xm <<= 1) s += __shfl_xor(s, xm, 64);
  __shared__ float part[4];
  __shared__ float smu, svar;
  if ((t & 63) == 0) part[t >> 6] = s;
  __syncthreads();
  if (t == 0) smu = (part[0] + part[1] + part[2] + part[3]) * (1.0f / DMODEL);
  __syncthreads();
  const float mu = smu;
  const float d0 = x.x - mu, d1 = x.y - mu, d2 = x.z - mu, d3 = x.w - mu;
  float s2 = d0 * d0 + d1 * d1 + d2 * d2 + d3 * d3;
#pragma unroll
  for (int xm = 1; xm < 64; xm <<= 1) s2 += __shfl_xor(s2, xm, 64);
  if ((t & 63) == 0) part[t >> 6] = s2;
  __syncthreads();
  if (t == 0) svar = (part[0] + part[1] + part[2] + part[3]) * (1.0f / DMODEL);
  __syncthreads();
  const float inv = rsqrtf(svar + 1e-6f);
  float4 g = *(const float4*)&gamma[t << 2];
  float4 be = *(const float4*)&beta[t << 2];
  float4 o;
  o.x = d0 * inv * g.x + be.x;
  o.y = d1 * inv * g.y + be.y;
  o.z = d2 * inv * g.z + be.z;
  o.w = d3 * inv * g.w + be.w;
  *(float4*)&base[t << 2] = o;
}

extern "C" void kernel_launch(void* const* d_in, const int* in_sizes, int n_in,
                              void* d_out, int out_size, void* d_ws,
                              size_t ws_size, hipStream_t stream) {
  const float* q = (const float*)d_in[0];
  const float* k = (const float*)d_in[1];
  const float* v = (const float*)d_in[2];
  const int* mask = (const int*)d_in[3];
  const float* mean = (const float*)d_in[4];
  const float* stdv = (const float*)d_in[5];
  const float* w_qs = (const float*)d_in[6];
  const float* w_ks = (const float*)d_in[7];
  const float* w_vs = (const float*)d_in[8];
  const float* w_fc = (const float*)d_in[9];
  const float* gamma = (const float*)d_in[10];
  const float* beta = (const float*)d_in[11];
  float* out = (float*)d_out;

  // ws layout (114 MB):
  // prH 24 | prL 24 | wT_h 8 | wT_l 8 | xin-region 48 (-> O0,O1,ao after proj)
  // | mbits 1 | ML0 .5 | ML1 .5
  ushort* prH = (ushort*)d_ws;
  ushort* prL = prH + 3 * PLANE;
  ushort* wT_h = prL + 3 * PLANE;
  ushort* wT_l = wT_h + 4 * WPLANE;
  ushort* xinH = wT_l + 4 * WPLANE;
  ushort* xinL = xinH + 3 * PLANE;
  float* O0 = (float*)xinH;                  // 16 MB (alias xin, post-proj)
  float* O1 = O0 + PLANE;                    // 16 MB
  ushort* aoH = (ushort*)(O1 + PLANE);       // 8 MB
  ushort* aoL = aoH + PLANE;                 // 8 MB (ends at xin+48MB)
  uint* mbits = (uint*)(xinL + 3 * PLANE);   // 1 MB
  float* ML0 = (float*)(mbits + (size_t)BB * LQ * 64);
  float* ML1 = ML0 + (size_t)BB * NHEAD * LQ * 2;

  dim3 blk(256);
  const int n4 = MROWS * DMODEL / 4;

  pack_mask<<<2048, blk, 0, stream>>>(mask, mbits);
  conv_wT<<<dim3(16, 16, 4), blk, 0, stream>>>(w_qs, w_ks, w_vs, w_fc, wT_h, wT_l);
  conv_x3<<<dim3(512, 1, 3), blk, 0, stream>>>(q, k, v, xinH, xinL, n4);

  gemm_mfma<3><<<dim3(8, 32, 3), blk, 0, stream>>>(
      xinH, xinL, wT_h, wT_l, prH, prL, nullptr, nullptr);

  attn_mfma<<<dim3(16, 16, 2 * BB), blk, 0, stream>>>(
      prH, prL, prH + PLANE, prL + PLANE, prH + 2 * PLANE, prL + 2 * PLANE,
      mbits, mean, stdv, O0, ML0);

  merge_attn<<<MROWS, blk, 0, stream>>>(O0, O1, ML0, ML1, aoH, aoL);

  gemm_mfma<1><<<dim3(8, 32), blk, 0, stream>>>(
      aoH, aoL, wT_h + 3 * WPLANE, wT_l + 3 * WPLANE, nullptr, nullptr, out, q);
  ln_kernel<<<MROWS, blk, 0, stream>>>(out, gamma, beta);
}